// Round 1
// baseline (180.810 us; speedup 1.0000x reference)
//
#include <hip/hip_runtime.h>
#include <hip/hip_bf16.h>
#include <cmath>

#define NH   12
#define HD   64
#define HID  768
#define NB   2
#define SEQL 2048
#define ROWS 4096   // NB*SEQL
#define OUTW 1536   // NH*HD*2

static constexpr float NEGBIG = 1000000000000.0f;

typedef __attribute__((ext_vector_type(8)))  short short8;
typedef __attribute__((ext_vector_type(16))) float f32x16;

__device__ __forceinline__ unsigned short f2bf(float f) {
    unsigned int u = __builtin_bit_cast(unsigned int, f);
    u += 0x7FFFu + ((u >> 16) & 1u);   // round-to-nearest-even
    return (unsigned short)(u >> 16);
}

// ---- K0: f32 -> bf16 bulk convert (vectorized) ----
__global__ void k_convert(const float* __restrict__ in, unsigned short* __restrict__ out, int n4) {
    int stride = gridDim.x * blockDim.x;
    for (int i = blockIdx.x * blockDim.x + threadIdx.x; i < n4; i += stride) {
        float4 v = reinterpret_cast<const float4*>(in)[i];
        ushort4 o;
        o.x = f2bf(v.x); o.y = f2bf(v.y); o.z = f2bf(v.z); o.w = f2bf(v.w);
        reinterpret_cast<ushort4*>(out)[i] = o;
    }
}

// ---- K0b: rope tables: tab[n*32+i] = (sin(n*theta_i), cos(n*theta_i)) ----
__global__ void k_rtab(float2* __restrict__ tab) {
    int idx = blockIdx.x * blockDim.x + threadIdx.x;  // 65536 threads
    int n = idx >> 5, i = idx & 31;
    float theta = powf(10000.0f, -(float)i / 32.0f);
    float ang = (float)n * theta;
    tab[idx] = make_float2(sinf(ang), cosf(ang));
}

// ---- K1: projection GEMM (bf16 MFMA) + bias + RoPE -> Qbf, Kbf [b][h][n][d] ----
__global__ __launch_bounds__(256) void k_proj_rope(
    const unsigned short* __restrict__ Xbf,   // [4096][768] bf16
    const unsigned short* __restrict__ Wbf,   // [1536][768] bf16
    const float*  __restrict__ bias,          // [1536]
    const float2* __restrict__ rtab,          // [2048][32]
    unsigned short* __restrict__ Qbf,         // [2][12][2048][64] bf16
    unsigned short* __restrict__ Kbf)
{
    const int head = blockIdx.x;      // 0..11
    const int row0 = blockIdx.y * 64; // global row base in [0,4096)
    const int tid  = threadIdx.x;
    const int lane = tid & 63;
    const int w    = tid >> 6;
    const int rowHalf = w & 1, colHalf = w >> 1;
    const int l31 = lane & 31, lhi = lane >> 5;

    f32x16 acc0, acc1;
#pragma unroll
    for (int i = 0; i < 16; ++i) { acc0[i] = 0.0f; acc1[i] = 0.0f; }

    const int o0 = head * 128 + colHalf * 64;
    const unsigned short* Arow  = Xbf + (size_t)(row0 + rowHalf * 32 + l31) * HID + 8 * lhi;
    const unsigned short* Brow0 = Wbf + (size_t)(o0 + l31) * HID + 8 * lhi;
    const unsigned short* Brow1 = Wbf + (size_t)(o0 + 32 + l31) * HID + 8 * lhi;

#pragma unroll 4
    for (int kk = 0; kk < HID; kk += 16) {
        short8 a  = *reinterpret_cast<const short8*>(Arow  + kk);
        short8 b0 = *reinterpret_cast<const short8*>(Brow0 + kk);
        short8 b1 = *reinterpret_cast<const short8*>(Brow1 + kk);
        acc0 = __builtin_amdgcn_mfma_f32_32x32x16_bf16(a, b0, acc0, 0, 0, 0);
        acc1 = __builtin_amdgcn_mfma_f32_32x32x16_bf16(a, b1, acc1, 0, 0, 0);
    }

    __shared__ float hs[64][132];   // 64 rows x 128 cols (one head: q|k), +4 pad
#pragma unroll
    for (int r = 0; r < 16; ++r) {
        int rr  = (r & 3) + 8 * (r >> 2) + 4 * lhi;  // 0..31
        int row = rowHalf * 32 + rr;
        hs[row][colHalf * 64 + l31]      = acc0[r];
        hs[row][colHalf * 64 + 32 + l31] = acc1[r];
    }
    __syncthreads();

    // RoPE + bias + bf16 store. 8192 elements / 256 threads = 32 each.
#pragma unroll 4
    for (int j = 0; j < 32; ++j) {
        int e   = tid + 256 * j;     // 0..8191
        int row = e >> 7;            // 0..63
        int col = e & 127;           // 0..127
        int grow = row0 + row;
        int bI  = grow >> 11;
        int n   = grow & 2047;
        int isK = col >> 6;
        int d   = col & 63;
        float v  = hs[row][col] + bias[head * 128 + col];
        int   p  = (d < 32) ? (2 * d + 1) : (2 * d - 64);
        float pv = hs[row][isK * 64 + p] + bias[head * 128 + isK * 64 + p];
        float sg = (d < 32) ? -1.0f : 1.0f;
        float2 sc = rtab[n * 32 + (d >> 1)];
        float ov = v * sc.y + sg * pv * sc.x;
        size_t idx = ((size_t)(bI * NH + head) * SEQL + n) * HD + d;
        (isK ? Kbf : Qbf)[idx] = f2bf(ov);
    }
}

// ---- K2: logits = QK^T, mask + tril + scale, f32 out ----
__global__ __launch_bounds__(256) void k_logits(
    const unsigned short* __restrict__ Qbf,
    const unsigned short* __restrict__ Kbf,
    const int* __restrict__ mask,    // [2][2048]
    float* __restrict__ out)         // [2][12][2048][2048]
{
    const int mt = blockIdx.x, nt = blockIdx.y, bh = blockIdx.z;
    const int bI = bh / NH;
    const int tid = threadIdx.x;
    const int lane = tid & 63;
    const int w = tid >> 6;
    const int rowHalf = w & 1, colHalf = w >> 1;
    const int l31 = lane & 31, lhi = lane >> 5;
    const int n0 = nt * 64 + rowHalf * 32;
    const int m0 = mt * 64 + colHalf * 32;

    const int   mcol = m0 + l31;
    const float padf = (float)mask[bI * SEQL + mcol];

    f32x16 acc;
#pragma unroll
    for (int i = 0; i < 16; ++i) acc[i] = 0.0f;

    // tile entirely strictly-below-diagonal (all m < all n): logit-independent output
    const bool fullmask = (mt * 64 + 63) < (nt * 64);
    if (!fullmask) {
        const unsigned short* Aq = Qbf + ((size_t)bh * SEQL + n0 + l31) * HD + 8 * lhi;
        const unsigned short* Bk = Kbf + ((size_t)bh * SEQL + m0 + l31) * HD + 8 * lhi;
#pragma unroll
        for (int t = 0; t < 4; ++t) {
            short8 a = *reinterpret_cast<const short8*>(Aq + 16 * t);
            short8 b = *reinterpret_cast<const short8*>(Bk + 16 * t);
            acc = __builtin_amdgcn_mfma_f32_32x32x16_bf16(a, b, acc, 0, 0, 0);
        }
    }

    float* outbase = out + (size_t)bh * SEQL * SEQL;
#pragma unroll
    for (int r = 0; r < 16; ++r) {
        int nrow = n0 + (r & 3) + 8 * (r >> 2) + 4 * lhi;
        float logit = fullmask ? 0.0f : acc[r];
        float v = logit * padf - (1.0f - padf) * NEGBIG;
        if (mcol < nrow) v -= NEGBIG;
        outbase[(size_t)nrow * SEQL + mcol] = v * 0.125f;
    }
}

extern "C" void kernel_launch(void* const* d_in, const int* in_sizes, int n_in,
                              void* d_out, int out_size, void* d_ws, size_t ws_size,
                              hipStream_t stream) {
    const float* x    = (const float*)d_in[0];
    const int*   mask = (const int*)d_in[1];
    const float* W    = (const float*)d_in[2];
    const float* bias = (const float*)d_in[3];
    float* out = (float*)d_out;

    char* ws = (char*)d_ws;
    unsigned short* Xbf = (unsigned short*)(ws);                 // 6,291,456 B
    unsigned short* Wbf = (unsigned short*)(ws + 6291456);       // 2,359,296 B
    unsigned short* Qbf = (unsigned short*)(ws + 8650752);       // 6,291,456 B
    unsigned short* Kbf = (unsigned short*)(ws + 14942208);      // 6,291,456 B
    float2*         rtab = (float2*)(ws + 21233664);             //   524,288 B

    k_convert<<<dim3(2048), dim3(256), 0, stream>>>(x, Xbf, ROWS * HID / 4);
    k_convert<<<dim3(1152), dim3(256), 0, stream>>>(W, Wbf, OUTW * HID / 4);
    k_rtab<<<dim3(256), dim3(256), 0, stream>>>(rtab);
    k_proj_rope<<<dim3(12, 64), dim3(256), 0, stream>>>(Xbf, Wbf, bias, rtab, Qbf, Kbf);
    k_logits<<<dim3(32, 32, 24), dim3(256), 0, stream>>>(Qbf, Kbf, mask, out);
}

// Round 3
// 145.119 us; speedup vs baseline: 1.2459x; 1.2459x over previous
//
#include <hip/hip_runtime.h>
#include <hip/hip_bf16.h>
#include <cmath>

#define NH   12
#define HD   64
#define HID  768
#define NB   2
#define SEQL 2048
#define ROWS 4096   // NB*SEQL
#define OUTW 1536   // NH*HD*2

static constexpr float NEGBIG = 1000000000000.0f;

typedef __attribute__((ext_vector_type(4)))  float f32x4;
typedef __attribute__((ext_vector_type(8)))  short short8;
typedef __attribute__((ext_vector_type(16))) float f32x16;

__device__ __forceinline__ unsigned short f2bf(float f) {
    unsigned int u = __builtin_bit_cast(unsigned int, f);
    u += 0x7FFFu + ((u >> 16) & 1u);   // round-to-nearest-even
    return (unsigned short)(u >> 16);
}

// ---- K0: f32 -> bf16 bulk convert (vectorized) ----
__global__ void k_convert(const float* __restrict__ in, unsigned short* __restrict__ out, int n4) {
    int stride = gridDim.x * blockDim.x;
    for (int i = blockIdx.x * blockDim.x + threadIdx.x; i < n4; i += stride) {
        float4 v = reinterpret_cast<const float4*>(in)[i];
        ushort4 o;
        o.x = f2bf(v.x); o.y = f2bf(v.y); o.z = f2bf(v.z); o.w = f2bf(v.w);
        reinterpret_cast<ushort4*>(out)[i] = o;
    }
}

// ---- K0b: rope tables: tab[n*32+i] = (sin(n*theta_i), cos(n*theta_i)) ----
__global__ void k_rtab(float2* __restrict__ tab) {
    int idx = blockIdx.x * blockDim.x + threadIdx.x;  // 65536 threads
    int n = idx >> 5, i = idx & 31;
    float theta = exp2f(-(float)i * (13.287712379549449f / 32.0f)); // 10000^(-i/32)
    float ang = (float)n * theta;
    tab[idx] = make_float2(sinf(ang), cosf(ang));
}

// ---- K1: projection GEMM (bf16 MFMA) + bias + RoPE -> Qbf, Kbf [b][h][n][d] ----
__global__ __launch_bounds__(256) void k_proj_rope(
    const unsigned short* __restrict__ Xbf,   // [4096][768] bf16
    const unsigned short* __restrict__ Wbf,   // [1536][768] bf16
    const float*  __restrict__ bias,          // [1536]
    const float2* __restrict__ rtab,          // [2048][32]
    unsigned short* __restrict__ Qbf,         // [2][12][2048][64] bf16
    unsigned short* __restrict__ Kbf)
{
    const int head = blockIdx.x;      // 0..11
    const int row0 = blockIdx.y * 64; // global row base in [0,4096)
    const int tid  = threadIdx.x;
    const int lane = tid & 63;
    const int w    = tid >> 6;
    const int rowHalf = w & 1, colHalf = w >> 1;
    const int l31 = lane & 31, lhi = lane >> 5;

    f32x16 acc0, acc1;
#pragma unroll
    for (int i = 0; i < 16; ++i) { acc0[i] = 0.0f; acc1[i] = 0.0f; }

    const int o0 = head * 128 + colHalf * 64;
    const unsigned short* Arow  = Xbf + (size_t)(row0 + rowHalf * 32 + l31) * HID + 8 * lhi;
    const unsigned short* Brow0 = Wbf + (size_t)(o0 + l31) * HID + 8 * lhi;
    const unsigned short* Brow1 = Wbf + (size_t)(o0 + 32 + l31) * HID + 8 * lhi;

#pragma unroll 4
    for (int kk = 0; kk < HID; kk += 16) {
        short8 a  = *reinterpret_cast<const short8*>(Arow  + kk);
        short8 b0 = *reinterpret_cast<const short8*>(Brow0 + kk);
        short8 b1 = *reinterpret_cast<const short8*>(Brow1 + kk);
        acc0 = __builtin_amdgcn_mfma_f32_32x32x16_bf16(a, b0, acc0, 0, 0, 0);
        acc1 = __builtin_amdgcn_mfma_f32_32x32x16_bf16(a, b1, acc1, 0, 0, 0);
    }

    __shared__ float hs[64][132];   // 64 rows x 128 cols (one head: q|k), +4 pad
#pragma unroll
    for (int r = 0; r < 16; ++r) {
        int rr  = (r & 3) + 8 * (r >> 2) + 4 * lhi;  // 0..31
        int row = rowHalf * 32 + rr;
        hs[row][colHalf * 64 + l31]      = acc0[r];
        hs[row][colHalf * 64 + 32 + l31] = acc1[r];
    }
    __syncthreads();

    // RoPE + bias + bf16 store. 8192 elements / 256 threads = 32 each.
#pragma unroll 4
    for (int j = 0; j < 32; ++j) {
        int e   = tid + 256 * j;     // 0..8191
        int row = e >> 7;            // 0..63
        int col = e & 127;           // 0..127
        int grow = row0 + row;
        int bI  = grow >> 11;
        int n   = grow & 2047;
        int isK = col >> 6;
        int d   = col & 63;
        float v  = hs[row][col] + bias[head * 128 + col];
        int   p  = (d < 32) ? (2 * d + 1) : (2 * d - 64);
        float pv = hs[row][isK * 64 + p] + bias[head * 128 + isK * 64 + p];
        float sg = (d < 32) ? -1.0f : 1.0f;
        float2 sc = rtab[n * 32 + (d >> 1)];
        float ov = v * sc.y + sg * pv * sc.x;
        size_t idx = ((size_t)(bI * NH + head) * SEQL + n) * HD + d;
        (isK ? Kbf : Qbf)[idx] = f2bf(ov);
    }
}

// ---- K2: logits = QK^T, mask + tril + scale, f32 out. 128x128 tile/block ----
__global__ __launch_bounds__(256) void k_logits(
    const unsigned short* __restrict__ Qbf,
    const unsigned short* __restrict__ Kbf,
    const int* __restrict__ mask,    // [2][2048]
    float* __restrict__ out)         // [2][12][2048][2048]
{
    const int mt = blockIdx.x, nt = blockIdx.y, bh = blockIdx.z;
    const int bI = bh / NH;
    const int tid = threadIdx.x;
    float* outbase = out + (size_t)bh * SEQL * SEQL;

    if (mt < nt) {
        // Tile entirely strictly-below-diagonal: output independent of logits.
        // Pure streaming f32x4 non-temporal write.
        const int cg = tid & 31;        // column group -> 4 consecutive cols
        const int r0 = tid >> 5;        // 0..7
        const int m0 = mt * 128 + cg * 4;
        const int4 mi = *reinterpret_cast<const int4*>(mask + bI * SEQL + m0);
        f32x4 v;
        v.x = ((float)mi.x - 2.0f) * (NEGBIG * 0.125f);
        v.y = ((float)mi.y - 2.0f) * (NEGBIG * 0.125f);
        v.z = ((float)mi.z - 2.0f) * (NEGBIG * 0.125f);
        v.w = ((float)mi.w - 2.0f) * (NEGBIG * 0.125f);
        float* ob = outbase + (size_t)(nt * 128) * SEQL + m0;
#pragma unroll
        for (int j = 0; j < 16; ++j) {
            int row = r0 + 8 * j;       // 0..127
            __builtin_nontemporal_store(v, reinterpret_cast<f32x4*>(ob + (size_t)row * SEQL));
        }
        return;
    }

    const int lane = tid & 63;
    const int w = tid >> 6;
    const int wn = (w & 1) * 64;
    const int wm = (w >> 1) * 64;
    const int l31 = lane & 31, lhi = lane >> 5;
    const int n0 = nt * 128 + wn;
    const int m0 = mt * 128 + wm;

    f32x16 acc[2][2];
#pragma unroll
    for (int i = 0; i < 2; ++i)
#pragma unroll
        for (int j = 0; j < 2; ++j)
#pragma unroll
            for (int r = 0; r < 16; ++r) acc[i][j][r] = 0.0f;

    const unsigned short* Aq = Qbf + ((size_t)bh * SEQL + n0 + l31) * HD + 8 * lhi;
    const unsigned short* Bk = Kbf + ((size_t)bh * SEQL + m0 + l31) * HD + 8 * lhi;
#pragma unroll
    for (int t = 0; t < 4; ++t) {
        short8 a0 = *reinterpret_cast<const short8*>(Aq + 16 * t);
        short8 a1 = *reinterpret_cast<const short8*>(Aq + 32 * HD + 16 * t);
        short8 b0 = *reinterpret_cast<const short8*>(Bk + 16 * t);
        short8 b1 = *reinterpret_cast<const short8*>(Bk + 32 * HD + 16 * t);
        acc[0][0] = __builtin_amdgcn_mfma_f32_32x32x16_bf16(a0, b0, acc[0][0], 0, 0, 0);
        acc[0][1] = __builtin_amdgcn_mfma_f32_32x32x16_bf16(a0, b1, acc[0][1], 0, 0, 0);
        acc[1][0] = __builtin_amdgcn_mfma_f32_32x32x16_bf16(a1, b0, acc[1][0], 0, 0, 0);
        acc[1][1] = __builtin_amdgcn_mfma_f32_32x32x16_bf16(a1, b1, acc[1][1], 0, 0, 0);
    }

#pragma unroll
    for (int j = 0; j < 2; ++j) {
        const int mcol = m0 + j * 32 + l31;
        const float padf = (float)mask[bI * SEQL + mcol];
        const float base = -(1.0f - padf) * NEGBIG;
#pragma unroll
        for (int i = 0; i < 2; ++i) {
#pragma unroll
            for (int r = 0; r < 16; ++r) {
                int nrow = n0 + i * 32 + (r & 3) + 8 * (r >> 2) + 4 * lhi;
                float v = acc[i][j][r] * padf + base;
                if (mcol < nrow) v -= NEGBIG;
                __builtin_nontemporal_store(v * 0.125f, outbase + (size_t)nrow * SEQL + mcol);
            }
        }
    }
}

extern "C" void kernel_launch(void* const* d_in, const int* in_sizes, int n_in,
                              void* d_out, int out_size, void* d_ws, size_t ws_size,
                              hipStream_t stream) {
    const float* x    = (const float*)d_in[0];
    const int*   mask = (const int*)d_in[1];
    const float* W    = (const float*)d_in[2];
    const float* bias = (const float*)d_in[3];
    float* out = (float*)d_out;

    char* ws = (char*)d_ws;
    unsigned short* Xbf = (unsigned short*)(ws);                 // 6,291,456 B
    unsigned short* Wbf = (unsigned short*)(ws + 6291456);       // 2,359,296 B
    unsigned short* Qbf = (unsigned short*)(ws + 8650752);       // 6,291,456 B
    unsigned short* Kbf = (unsigned short*)(ws + 14942208);      // 6,291,456 B
    float2*         rtab = (float2*)(ws + 21233664);             //   524,288 B

    k_convert<<<dim3(2048), dim3(256), 0, stream>>>(x, Xbf, ROWS * HID / 4);
    k_convert<<<dim3(1152), dim3(256), 0, stream>>>(W, Wbf, OUTW * HID / 4);
    k_rtab<<<dim3(256), dim3(256), 0, stream>>>(rtab);
    k_proj_rope<<<dim3(12, 64), dim3(256), 0, stream>>>(Xbf, Wbf, bias, rtab, Qbf, Kbf);
    k_logits<<<dim3(16, 16, 24), dim3(256), 0, stream>>>(Qbf, Kbf, mask, out);
}

// Round 4
// 141.542 us; speedup vs baseline: 1.2774x; 1.0253x over previous
//
#include <hip/hip_runtime.h>
#include <hip/hip_bf16.h>
#include <cmath>

#define NH   12
#define HD   64
#define HID  768
#define NB   2
#define SEQL 2048
#define ROWS 4096   // NB*SEQL
#define OUTW 1536   // NH*HD*2

static constexpr float NEGBIG = 1000000000000.0f;

typedef __attribute__((ext_vector_type(4)))  float f32x4;
typedef __attribute__((ext_vector_type(8)))  short short8;
typedef __attribute__((ext_vector_type(16))) float f32x16;

__device__ __forceinline__ unsigned short f2bf(float f) {
    unsigned int u = __builtin_bit_cast(unsigned int, f);
    u += 0x7FFFu + ((u >> 16) & 1u);   // round-to-nearest-even
    return (unsigned short)(u >> 16);
}

// ---- K0: fused prep: convert X, convert W (f32->bf16), build rope table ----
#define XQ (ROWS * HID / 4)          // 786432 float4 groups
#define WQ (OUTW * HID / 4)          // 294912
#define RQ (SEQL * 32)               // 65536
__global__ void k_prep(const float* __restrict__ X, const float* __restrict__ W,
                       unsigned short* __restrict__ Xbf, unsigned short* __restrict__ Wbf,
                       float2* __restrict__ rtab) {
    int i = blockIdx.x * blockDim.x + threadIdx.x;
    if (i < XQ + WQ) {
        const float* src = (i < XQ) ? X : W;
        unsigned short* dst = (i < XQ) ? Xbf : Wbf;
        int k = (i < XQ) ? i : i - XQ;
        float4 v = reinterpret_cast<const float4*>(src)[k];
        ushort4 o;
        o.x = f2bf(v.x); o.y = f2bf(v.y); o.z = f2bf(v.z); o.w = f2bf(v.w);
        reinterpret_cast<ushort4*>(dst)[k] = o;
    } else if (i < XQ + WQ + RQ) {
        int idx = i - (XQ + WQ);
        int n = idx >> 5, d = idx & 31;
        float theta = exp2f(-(float)d * (13.287712379549449f / 32.0f)); // 10000^(-d/32)
        float ang = (float)n * theta;
        rtab[idx] = make_float2(sinf(ang), cosf(ang));
    }
}

// ---- K1: projection GEMM (bf16 MFMA) + bias + RoPE -> Qbf, Kbf [b][h][n][d] ----
__global__ __launch_bounds__(256) void k_proj_rope(
    const unsigned short* __restrict__ Xbf,   // [4096][768] bf16
    const unsigned short* __restrict__ Wbf,   // [1536][768] bf16
    const float*  __restrict__ bias,          // [1536]
    const float2* __restrict__ rtab,          // [2048][32]
    unsigned short* __restrict__ Qbf,         // [2][12][2048][64] bf16
    unsigned short* __restrict__ Kbf)
{
    const int head = blockIdx.x;      // 0..11
    const int row0 = blockIdx.y * 64; // global row base in [0,4096)
    const int tid  = threadIdx.x;
    const int lane = tid & 63;
    const int w    = tid >> 6;
    const int rowHalf = w & 1, colHalf = w >> 1;
    const int l31 = lane & 31, lhi = lane >> 5;

    f32x16 acc0, acc1;
#pragma unroll
    for (int i = 0; i < 16; ++i) { acc0[i] = 0.0f; acc1[i] = 0.0f; }

    const int o0 = head * 128 + colHalf * 64;
    const unsigned short* Arow  = Xbf + (size_t)(row0 + rowHalf * 32 + l31) * HID + 8 * lhi;
    const unsigned short* Brow0 = Wbf + (size_t)(o0 + l31) * HID + 8 * lhi;
    const unsigned short* Brow1 = Wbf + (size_t)(o0 + 32 + l31) * HID + 8 * lhi;

#pragma unroll 4
    for (int kk = 0; kk < HID; kk += 16) {
        short8 a  = *reinterpret_cast<const short8*>(Arow  + kk);
        short8 b0 = *reinterpret_cast<const short8*>(Brow0 + kk);
        short8 b1 = *reinterpret_cast<const short8*>(Brow1 + kk);
        acc0 = __builtin_amdgcn_mfma_f32_32x32x16_bf16(a, b0, acc0, 0, 0, 0);
        acc1 = __builtin_amdgcn_mfma_f32_32x32x16_bf16(a, b1, acc1, 0, 0, 0);
    }

    __shared__ float hs[64][132];   // 64 rows x 128 cols (one head: q|k), +4 pad
#pragma unroll
    for (int r = 0; r < 16; ++r) {
        int rr  = (r & 3) + 8 * (r >> 2) + 4 * lhi;  // 0..31
        int row = rowHalf * 32 + rr;
        hs[row][colHalf * 64 + l31]      = acc0[r];
        hs[row][colHalf * 64 + 32 + l31] = acc1[r];
    }
    __syncthreads();

    // RoPE + bias + bf16 store. 8192 elements / 256 threads = 32 each.
#pragma unroll 4
    for (int j = 0; j < 32; ++j) {
        int e   = tid + 256 * j;     // 0..8191
        int row = e >> 7;            // 0..63
        int col = e & 127;           // 0..127
        int grow = row0 + row;
        int bI  = grow >> 11;
        int n   = grow & 2047;
        int isK = col >> 6;
        int d   = col & 63;
        float v  = hs[row][col] + bias[head * 128 + col];
        int   p  = (d < 32) ? (2 * d + 1) : (2 * d - 64);
        float pv = hs[row][isK * 64 + p] + bias[head * 128 + isK * 64 + p];
        float sg = (d < 32) ? -1.0f : 1.0f;
        float2 sc = rtab[n * 32 + (d >> 1)];
        float ov = v * sc.y + sg * pv * sc.x;
        size_t idx = ((size_t)(bI * NH + head) * SEQL + n) * HD + d;
        (isK ? Kbf : Qbf)[idx] = f2bf(ov);
    }
}

// ---- K2: logits = QK^T, mask + tril + scale, f32 out. 128x128 tile/block ----
__global__ __launch_bounds__(256) void k_logits(
    const unsigned short* __restrict__ Qbf,
    const unsigned short* __restrict__ Kbf,
    const int* __restrict__ mask,    // [2][2048]
    float* __restrict__ out)         // [2][12][2048][2048]
{
    const int mt = blockIdx.x, nt = blockIdx.y, bh = blockIdx.z;
    const int bI = bh / NH;
    const int tid = threadIdx.x;
    float* outbase = out + (size_t)bh * SEQL * SEQL;

    if (mt < nt) {
        // Tile entirely strictly-below-diagonal: output independent of logits.
        const int cg = tid & 31;        // column group -> 4 consecutive cols
        const int r0 = tid >> 5;        // 0..7
        const int m0 = mt * 128 + cg * 4;
        const int4 mi = *reinterpret_cast<const int4*>(mask + bI * SEQL + m0);
        f32x4 v;
        v.x = ((float)mi.x - 2.0f) * (NEGBIG * 0.125f);
        v.y = ((float)mi.y - 2.0f) * (NEGBIG * 0.125f);
        v.z = ((float)mi.z - 2.0f) * (NEGBIG * 0.125f);
        v.w = ((float)mi.w - 2.0f) * (NEGBIG * 0.125f);
        float* ob = outbase + (size_t)(nt * 128) * SEQL + m0;
#pragma unroll
        for (int j = 0; j < 16; ++j) {
            int row = r0 + 8 * j;       // 0..127
            __builtin_nontemporal_store(v, reinterpret_cast<f32x4*>(ob + (size_t)row * SEQL));
        }
        return;
    }

    const int lane = tid & 63;
    const int w = tid >> 6;
    const int rowHalf = w & 1, colHalf = w >> 1;
    const int l31 = lane & 31, lhi = lane >> 5;
    const int n0 = nt * 128 + rowHalf * 64;
    const int m0 = mt * 128 + colHalf * 64;

    f32x16 acc[2][2];
#pragma unroll
    for (int i = 0; i < 2; ++i)
#pragma unroll
        for (int j = 0; j < 2; ++j)
#pragma unroll
            for (int r = 0; r < 16; ++r) acc[i][j][r] = 0.0f;

    const unsigned short* Aq = Qbf + ((size_t)bh * SEQL + n0 + l31) * HD + 8 * lhi;
    const unsigned short* Bk = Kbf + ((size_t)bh * SEQL + m0 + l31) * HD + 8 * lhi;
#pragma unroll
    for (int t = 0; t < 4; ++t) {
        short8 a0 = *reinterpret_cast<const short8*>(Aq + 16 * t);
        short8 a1 = *reinterpret_cast<const short8*>(Aq + 32 * HD + 16 * t);
        short8 b0 = *reinterpret_cast<const short8*>(Bk + 16 * t);
        short8 b1 = *reinterpret_cast<const short8*>(Bk + 32 * HD + 16 * t);
        acc[0][0] = __builtin_amdgcn_mfma_f32_32x32x16_bf16(a0, b0, acc[0][0], 0, 0, 0);
        acc[0][1] = __builtin_amdgcn_mfma_f32_32x32x16_bf16(a0, b1, acc[0][1], 0, 0, 0);
        acc[1][0] = __builtin_amdgcn_mfma_f32_32x32x16_bf16(a1, b0, acc[1][0], 0, 0, 0);
        acc[1][1] = __builtin_amdgcn_mfma_f32_32x32x16_bf16(a1, b1, acc[1][1], 0, 0, 0);
    }

    // LDS-transpose epilogue: two 32-row slabs (i = 0,1), f32x4 NT stores.
    __shared__ float tl[64][128];   // 32 KB
#pragma unroll
    for (int i = 0; i < 2; ++i) {
#pragma unroll
        for (int j = 0; j < 2; ++j) {
#pragma unroll
            for (int r = 0; r < 16; ++r) {
                int rr = (r & 3) + 8 * (r >> 2) + 4 * lhi;    // 0..31
                tl[rowHalf * 32 + rr][colHalf * 64 + j * 32 + l31] = acc[i][j][r];
            }
        }
        __syncthreads();
        // 64 rows x 128 cols = 2048 f32x4; 256 threads x 8 iters
#pragma unroll
        for (int it = 0; it < 8; ++it) {
            int f   = tid + 256 * it;      // 0..2047
            int lr  = f >> 5;              // 0..63
            int cg  = f & 31;              // 0..31 -> 4 cols
            int grow = nt * 128 + (lr >> 5) * 64 + i * 32 + (lr & 31);
            int gcol = mt * 128 + cg * 4;
            const int4 mi = *reinterpret_cast<const int4*>(mask + bI * SEQL + gcol);
            f32x4 v = *reinterpret_cast<const f32x4*>(&tl[lr][cg * 4]);
            float pads[4] = {(float)mi.x, (float)mi.y, (float)mi.z, (float)mi.w};
#pragma unroll
            for (int e = 0; e < 4; ++e) {
                float vv = v[e] * pads[e] - (1.0f - pads[e]) * NEGBIG;
                if (gcol + e < grow) vv -= NEGBIG;
                v[e] = vv * 0.125f;
            }
            __builtin_nontemporal_store(v, reinterpret_cast<f32x4*>(outbase + (size_t)grow * SEQL + gcol));
        }
        __syncthreads();
    }
}

extern "C" void kernel_launch(void* const* d_in, const int* in_sizes, int n_in,
                              void* d_out, int out_size, void* d_ws, size_t ws_size,
                              hipStream_t stream) {
    const float* x    = (const float*)d_in[0];
    const int*   mask = (const int*)d_in[1];
    const float* W    = (const float*)d_in[2];
    const float* bias = (const float*)d_in[3];
    float* out = (float*)d_out;

    char* ws = (char*)d_ws;
    unsigned short* Xbf = (unsigned short*)(ws);                 // 6,291,456 B
    unsigned short* Wbf = (unsigned short*)(ws + 6291456);       // 2,359,296 B
    unsigned short* Qbf = (unsigned short*)(ws + 8650752);       // 6,291,456 B
    unsigned short* Kbf = (unsigned short*)(ws + 14942208);      // 6,291,456 B
    float2*         rtab = (float2*)(ws + 21233664);             //   524,288 B

    const int prep_items = XQ + WQ + RQ;                         // 1,146,880
    k_prep<<<dim3((prep_items + 255) / 256), dim3(256), 0, stream>>>(x, W, Xbf, Wbf, rtab);
    k_proj_rope<<<dim3(12, 64), dim3(256), 0, stream>>>(Xbf, Wbf, bias, rtab, Qbf, Kbf);
    k_logits<<<dim3(16, 16, 24), dim3(256), 0, stream>>>(Qbf, Kbf, mask, out);
}

// Round 5
// 136.316 us; speedup vs baseline: 1.3264x; 1.0383x over previous
//
#include <hip/hip_runtime.h>
#include <hip/hip_bf16.h>
#include <cmath>

#define NH   12
#define HD   64
#define HID  768
#define NB   2
#define SEQL 2048
#define ROWS 4096   // NB*SEQL
#define OUTW 1536   // NH*HD*2

static constexpr float NEGBIG = 1000000000000.0f;

typedef __attribute__((ext_vector_type(4)))  float f32x4;
typedef __attribute__((ext_vector_type(8)))  short short8;
typedef __attribute__((ext_vector_type(16))) float f32x16;

__device__ __forceinline__ unsigned short f2bf(float f) {
    unsigned int u = __builtin_bit_cast(unsigned int, f);
    u += 0x7FFFu + ((u >> 16) & 1u);   // round-to-nearest-even
    return (unsigned short)(u >> 16);
}

// ---- K0: fused prep: convert X, convert W (f32->bf16), build rope table ----
#define XQ (ROWS * HID / 4)          // 786432 float4 groups
#define WQ (OUTW * HID / 4)          // 294912
#define RQ (SEQL * 32)               // 65536
__global__ void k_prep(const float* __restrict__ X, const float* __restrict__ W,
                       unsigned short* __restrict__ Xbf, unsigned short* __restrict__ Wbf,
                       float2* __restrict__ rtab) {
    int i = blockIdx.x * blockDim.x + threadIdx.x;
    if (i < XQ + WQ) {
        const float* src = (i < XQ) ? X : W;
        unsigned short* dst = (i < XQ) ? Xbf : Wbf;
        int k = (i < XQ) ? i : i - XQ;
        float4 v = reinterpret_cast<const float4*>(src)[k];
        ushort4 o;
        o.x = f2bf(v.x); o.y = f2bf(v.y); o.z = f2bf(v.z); o.w = f2bf(v.w);
        reinterpret_cast<ushort4*>(dst)[k] = o;
    } else if (i < XQ + WQ + RQ) {
        int idx = i - (XQ + WQ);
        int n = idx >> 5, d = idx & 31;
        float theta = exp2f(-(float)d * (13.287712379549449f / 32.0f)); // 10000^(-d/32)
        float ang = (float)n * theta;
        rtab[idx] = make_float2(sinf(ang), cosf(ang));
    }
}

// ---- K1: projection GEMM (bf16 MFMA, 128x128 tile, 2x2 acc/wave) + bias + RoPE ----
__global__ __launch_bounds__(256) void k_proj_rope(
    const unsigned short* __restrict__ Xbf,   // [4096][768] bf16
    const unsigned short* __restrict__ Wbf,   // [1536][768] bf16
    const float*  __restrict__ bias,          // [1536]
    const float2* __restrict__ rtab,          // [2048][32]
    unsigned short* __restrict__ Qbf,         // [2][12][2048][64] bf16
    unsigned short* __restrict__ Kbf)
{
    const int head = blockIdx.x;       // 0..11
    const int row0 = blockIdx.y * 128; // global row base in [0,4096)
    const int tid  = threadIdx.x;
    const int lane = tid & 63;
    const int w    = tid >> 6;
    const int wr = w & 1, wc = w >> 1;
    const int l31 = lane & 31, lhi = lane >> 5;

    f32x16 acc[2][2];
#pragma unroll
    for (int i = 0; i < 2; ++i)
#pragma unroll
        for (int j = 0; j < 2; ++j)
#pragma unroll
            for (int r = 0; r < 16; ++r) acc[i][j][r] = 0.0f;

    const int o0 = head * 128 + wc * 64;
    const unsigned short* A0 = Xbf + (size_t)(row0 + wr * 64 + l31) * HID + 8 * lhi;
    const unsigned short* B0 = Wbf + (size_t)(o0 + l31) * HID + 8 * lhi;

#pragma unroll 4
    for (int kk = 0; kk < HID; kk += 16) {
        short8 a0 = *reinterpret_cast<const short8*>(A0 + kk);
        short8 a1 = *reinterpret_cast<const short8*>(A0 + 32 * HID + kk);
        short8 b0 = *reinterpret_cast<const short8*>(B0 + kk);
        short8 b1 = *reinterpret_cast<const short8*>(B0 + 32 * HID + kk);
        acc[0][0] = __builtin_amdgcn_mfma_f32_32x32x16_bf16(a0, b0, acc[0][0], 0, 0, 0);
        acc[0][1] = __builtin_amdgcn_mfma_f32_32x32x16_bf16(a0, b1, acc[0][1], 0, 0, 0);
        acc[1][0] = __builtin_amdgcn_mfma_f32_32x32x16_bf16(a1, b0, acc[1][0], 0, 0, 0);
        acc[1][1] = __builtin_amdgcn_mfma_f32_32x32x16_bf16(a1, b1, acc[1][1], 0, 0, 0);
    }

    // RoPE epilogue in two 64-row slabs. hs cols: 0..63 = q, 64..127 = k.
    __shared__ float hs[64][132];
    for (int s = 0; s < 2; ++s) {
        if (wr == s) {
#pragma unroll
            for (int i = 0; i < 2; ++i)
#pragma unroll
                for (int j = 0; j < 2; ++j)
#pragma unroll
                    for (int r = 0; r < 16; ++r) {
                        int rr = (r & 3) + 8 * (r >> 2) + 4 * lhi;  // 0..31
                        hs[i * 32 + rr][wc * 64 + j * 32 + l31] = acc[i][j][r];
                    }
        }
        __syncthreads();
        // 64 rows x 32 pairs x 2 (q,k) = 4096 ushort2 items, 16 per thread
#pragma unroll 4
        for (int it = 0; it < 16; ++it) {
            int f   = tid + 256 * it;    // 0..4095
            int row = f >> 6;            // 0..63
            int u   = f & 63;
            int isK = u >> 5;
            int dp  = u & 31;            // pair index
            int d0  = 2 * dp, d1 = d0 + 1;
            int cb  = isK * 64;
            int grow = row0 + s * 64 + row;
            int bI = grow >> 11;
            int n  = grow & 2047;
            float2 sc = rtab[n * 32 + dp];
            float v0 = hs[row][cb + d0] + bias[head * 128 + cb + d0];
            float v1 = hs[row][cb + d1] + bias[head * 128 + cb + d1];
            int p0 = (d0 < 32) ? (2 * d0 + 1) : (2 * d0 - 64);
            int p1 = (d1 < 32) ? (2 * d1 + 1) : (2 * d1 - 64);
            float pv0 = hs[row][cb + p0] + bias[head * 128 + cb + p0];
            float pv1 = hs[row][cb + p1] + bias[head * 128 + cb + p1];
            float sg0 = (d0 < 32) ? -1.0f : 1.0f;
            float sg1 = (d1 < 32) ? -1.0f : 1.0f;
            ushort2 st;
            st.x = f2bf(v0 * sc.y + sg0 * pv0 * sc.x);
            st.y = f2bf(v1 * sc.y + sg1 * pv1 * sc.x);
            unsigned short* dst = isK ? (unsigned short*)Kbf : (unsigned short*)Qbf;
            size_t idx = ((size_t)(bI * NH + head) * SEQL + n) * HD + d0;
            *reinterpret_cast<ushort2*>(dst + idx) = st;
        }
        __syncthreads();
    }
}

// ---- K2: logits = QK^T, mask + tril + scale, f32 out. 128x128 tile/block ----
// 1D grid with XCD-bijective swizzle: 6144 = 8 XCDs * 768; each XCD owns 3 bh.
__global__ __launch_bounds__(256) void k_logits(
    const unsigned short* __restrict__ Qbf,
    const unsigned short* __restrict__ Kbf,
    const int* __restrict__ mask,    // [2][2048]
    float* __restrict__ out)         // [2][12][2048][2048]
{
    const int bid = blockIdx.x;
    const int newbid = (bid & 7) * 768 + (bid >> 3);
    const int bh = newbid >> 8;
    const int t  = newbid & 255;
    const int nt = t >> 4, mt = t & 15;
    const int bI = bh / NH;
    const int tid = threadIdx.x;
    float* outbase = out + (size_t)bh * SEQL * SEQL;

    if (mt < nt) {
        // Tile entirely strictly-below-diagonal: output independent of logits.
        const int cg = tid & 31;        // column group -> 4 consecutive cols
        const int r0 = tid >> 5;        // 0..7
        const int m0 = mt * 128 + cg * 4;
        const int4 mi = *reinterpret_cast<const int4*>(mask + bI * SEQL + m0);
        f32x4 v;
        v.x = ((float)mi.x - 2.0f) * (NEGBIG * 0.125f);
        v.y = ((float)mi.y - 2.0f) * (NEGBIG * 0.125f);
        v.z = ((float)mi.z - 2.0f) * (NEGBIG * 0.125f);
        v.w = ((float)mi.w - 2.0f) * (NEGBIG * 0.125f);
        float* ob = outbase + (size_t)(nt * 128) * SEQL + m0;
#pragma unroll
        for (int j = 0; j < 16; ++j) {
            int row = r0 + 8 * j;       // 0..127
            __builtin_nontemporal_store(v, reinterpret_cast<f32x4*>(ob + (size_t)row * SEQL));
        }
        return;
    }

    const int lane = tid & 63;
    const int w = tid >> 6;
    const int rowHalf = w & 1, colHalf = w >> 1;
    const int l31 = lane & 31, lhi = lane >> 5;
    const int n0 = nt * 128 + rowHalf * 64;
    const int m0 = mt * 128 + colHalf * 64;

    f32x16 acc[2][2];
#pragma unroll
    for (int i = 0; i < 2; ++i)
#pragma unroll
        for (int j = 0; j < 2; ++j)
#pragma unroll
            for (int r = 0; r < 16; ++r) acc[i][j][r] = 0.0f;

    const unsigned short* Aq = Qbf + ((size_t)bh * SEQL + n0 + l31) * HD + 8 * lhi;
    const unsigned short* Bk = Kbf + ((size_t)bh * SEQL + m0 + l31) * HD + 8 * lhi;
#pragma unroll
    for (int t2 = 0; t2 < 4; ++t2) {
        short8 a0 = *reinterpret_cast<const short8*>(Aq + 16 * t2);
        short8 a1 = *reinterpret_cast<const short8*>(Aq + 32 * HD + 16 * t2);
        short8 b0 = *reinterpret_cast<const short8*>(Bk + 16 * t2);
        short8 b1 = *reinterpret_cast<const short8*>(Bk + 32 * HD + 16 * t2);
        acc[0][0] = __builtin_amdgcn_mfma_f32_32x32x16_bf16(a0, b0, acc[0][0], 0, 0, 0);
        acc[0][1] = __builtin_amdgcn_mfma_f32_32x32x16_bf16(a0, b1, acc[0][1], 0, 0, 0);
        acc[1][0] = __builtin_amdgcn_mfma_f32_32x32x16_bf16(a1, b0, acc[1][0], 0, 0, 0);
        acc[1][1] = __builtin_amdgcn_mfma_f32_32x32x16_bf16(a1, b1, acc[1][1], 0, 0, 0);
    }

    // LDS-transpose epilogue: two 32-row slabs (i = 0,1), f32x4 NT stores.
    __shared__ float tl[64][128];   // 32 KB
#pragma unroll
    for (int i = 0; i < 2; ++i) {
#pragma unroll
        for (int j = 0; j < 2; ++j) {
#pragma unroll
            for (int r = 0; r < 16; ++r) {
                int rr = (r & 3) + 8 * (r >> 2) + 4 * lhi;    // 0..31
                tl[rowHalf * 32 + rr][colHalf * 64 + j * 32 + l31] = acc[i][j][r];
            }
        }
        __syncthreads();
        // 64 rows x 128 cols = 2048 f32x4; 256 threads x 8 iters
#pragma unroll
        for (int it = 0; it < 8; ++it) {
            int f   = tid + 256 * it;      // 0..2047
            int lr  = f >> 5;              // 0..63
            int cg  = f & 31;              // 0..31 -> 4 cols
            int grow = nt * 128 + (lr >> 5) * 64 + i * 32 + (lr & 31);
            int gcol = mt * 128 + cg * 4;
            const int4 mi = *reinterpret_cast<const int4*>(mask + bI * SEQL + gcol);
            f32x4 v = *reinterpret_cast<const f32x4*>(&tl[lr][cg * 4]);
            float pads[4] = {(float)mi.x, (float)mi.y, (float)mi.z, (float)mi.w};
#pragma unroll
            for (int e = 0; e < 4; ++e) {
                float vv = v[e] * pads[e] - (1.0f - pads[e]) * NEGBIG;
                if (gcol + e < grow) vv -= NEGBIG;
                v[e] = vv * 0.125f;
            }
            __builtin_nontemporal_store(v, reinterpret_cast<f32x4*>(outbase + (size_t)grow * SEQL + gcol));
        }
        __syncthreads();
    }
}

extern "C" void kernel_launch(void* const* d_in, const int* in_sizes, int n_in,
                              void* d_out, int out_size, void* d_ws, size_t ws_size,
                              hipStream_t stream) {
    const float* x    = (const float*)d_in[0];
    const int*   mask = (const int*)d_in[1];
    const float* W    = (const float*)d_in[2];
    const float* bias = (const float*)d_in[3];
    float* out = (float*)d_out;

    char* ws = (char*)d_ws;
    unsigned short* Xbf = (unsigned short*)(ws);                 // 6,291,456 B
    unsigned short* Wbf = (unsigned short*)(ws + 6291456);       // 2,359,296 B
    unsigned short* Qbf = (unsigned short*)(ws + 8650752);       // 6,291,456 B
    unsigned short* Kbf = (unsigned short*)(ws + 14942208);      // 6,291,456 B
    float2*         rtab = (float2*)(ws + 21233664);             //   524,288 B

    const int prep_items = XQ + WQ + RQ;                         // 1,146,880
    k_prep<<<dim3((prep_items + 255) / 256), dim3(256), 0, stream>>>(x, W, Xbf, Wbf, rtab);
    k_proj_rope<<<dim3(12, 32), dim3(256), 0, stream>>>(Xbf, Wbf, bias, rtab, Qbf, Kbf);
    k_logits<<<dim3(6144), dim3(256), 0, stream>>>(Qbf, Kbf, mask, out);
}